// Round 5
// baseline (7672.729 us; speedup 1.0000x reference)
//
#include <hip/hip_runtime.h>
#include <hip/hip_fp16.h>

typedef _Float16 f16x8 __attribute__((ext_vector_type(8)));
typedef float f32x4 __attribute__((ext_vector_type(4)));
typedef unsigned long long u64;

#define NT 128      // 2 waves per block -> 2 independent batch-chains
#define B_ 256
#define D_ 128
#define T_ 512
#define H_ 512

#define NG 8        // batch groups
#define CB 32       // blocks per group
#define BS 32       // batch per group (16 per wave-class)
#define HS 16       // h-cols per block
#define DS 4        // z-dims per block
#define GHSZ (NG * BS * H_)      // 131072 elems per h buffer

#define SC  2048.0f              // 2^11 prescale
#define S1  (1.0f/2048.0f)       // 2^-11
#define S2  (1.0f/4194304.0f)    // 2^-22

#define MFMA16(A,B,C) __builtin_amdgcn_mfma_f32_16x16x32_f16((A),(B),(C),0,0,0)
#define ALD(p)   __hip_atomic_load((p),  __ATOMIC_RELAXED, __HIP_MEMORY_SCOPE_AGENT)
#define AST(p,v) __hip_atomic_store((p),(v),__ATOMIC_RELAXED, __HIP_MEMORY_SCOPE_AGENT)

// fragment-tile offset: row R of [3H][H] weight, col k -> per-(block c, gate t,
// kt) tile of 16 rows x 32 k, laid out so lane (l16,quad) reads 16B at
// base + (l16*4+quad)*8, tiles consecutive in kt.  (proven by R4's Mlo path)
__device__ inline size_t tiled_off(int R, int k) {
    const int t = R >> 9, jj = R & 511;
    const int c = jj >> 4, l16 = jj & 15;
    const int kt = k >> 5, quad = (k >> 3) & 3, j = k & 7;
    return ((size_t)(((c * 3 + t) * 16 + kt) * 16 + l16) * 4 + quad) * 8 + j;
}

// ---------------- setup 1: M = W_ih @ fc_W, hi plain + lo(x2^11) tiled ------
__global__ __launch_bounds__(256)
void msd_setup_M(const float* __restrict__ W_ih, const float* __restrict__ fc_W,
                 _Float16* __restrict__ Mhi, _Float16* __restrict__ Mlo)
{
    const int r0 = (blockIdx.x >> 1) * 4;
    const int k  = ((blockIdx.x & 1) << 8) + threadIdx.x;
    for (int rr = 0; rr < 4; ++rr) {
        const int R = r0 + rr;
        const float* wrow = W_ih + (size_t)R * D_;
        float s = 0.0f;
        for (int d = 0; d < D_; ++d) s = fmaf(wrow[d], fc_W[(size_t)d * H_ + k], s);
        _Float16 hi = (_Float16)s;
        Mhi[(size_t)R * H_ + k] = hi;
        Mlo[tiled_off(R, k)] = (_Float16)((s - (float)hi) * SC);
    }
}

// ---------------- setup 2: WhhL = (W_hh - f16(W_hh)) x 2^11, tiled ----------
__global__ __launch_bounds__(256)
void msd_setup_WL(const float* __restrict__ W_hh, _Float16* __restrict__ WhhL)
{
    const int r0 = (blockIdx.x >> 1) * 4;
    const int k  = ((blockIdx.x & 1) << 8) + threadIdx.x;
    for (int rr = 0; rr < 4; ++rr) {
        const int R = r0 + rr;
        float w = W_hh[(size_t)R * H_ + k];
        _Float16 hi = (_Float16)w;
        WhhL[tiled_off(R, k)] = (_Float16)((w - (float)hi) * SC);
    }
}

// ---------------- main persistent GRU scan ---------------------------------
__global__ __launch_bounds__(NT, 1)   // 1 wave/EU min -> full VGPR budget
void msd_gru_kernel(const float* __restrict__ zin,
                    const float* __restrict__ W_ih,
                    const float* __restrict__ W_hh,
                    const float* __restrict__ b_ih,
                    const float* __restrict__ b_hh,
                    const float* __restrict__ fc_W,
                    const float* __restrict__ fc_b,
                    float* __restrict__ out,
                    unsigned short* __restrict__ h1_g,   // 2 x [NG][BS][H_]
                    unsigned short* __restrict__ h2_g,   // 2 x [NG][BS][H_]
                    const _Float16* __restrict__ Mhi_w,  // [3H][H] plain
                    const _Float16* __restrict__ Mlo_w,  // tiled
                    const _Float16* __restrict__ WhhL_w, // tiled
                    unsigned* __restrict__ cnt)
{
    const int g   = blockIdx.x & 7;
    const int c   = blockIdx.x >> 3;
    const int B0  = g * BS;
    const int j0  = c * HS;
    const int d0  = c * DS;

    const int tid  = threadIdx.x;
    const int wave = tid >> 6;
    const int lane = tid & 63;
    const int l16  = lane & 15;
    const int quad = lane >> 4;
    const int bm0  = wave * 16;

    // LDS: (48*2 + 5) * 512 * 2 B = 103,424 B.  XOR-swizzled chunks.
    __shared__ __attribute__((aligned(16))) _Float16 Whh_s[48 * 512];
    __shared__ __attribute__((aligned(16))) _Float16 Mhi_s[48 * 512];
    __shared__ __attribute__((aligned(16))) _Float16 fcW_s[5 * 512];  // row 4 = 0

    // ===== phase 0: z0 scratch (reuse Whh_s region), bootstrap state =========
    float* z0s = (float*)Whh_s;   // 16 KB
    for (int idx = tid; idx < BS * D_; idx += NT) {
        int b = idx >> 7, d = idx & (D_ - 1);
        z0s[idx] = zin[(size_t)(B0 + b) * (D_ * T_) + (size_t)d * T_];
    }
    __syncthreads();

    f32x4 zfrag;
    #pragma unroll
    for (int e = 0; e < 4; ++e)
        zfrag[e] = (l16 < DS) ? z0s[(bm0 + quad * 4 + e) * D_ + d0 + l16] : 0.0f;
    if (l16 < DS) {
        #pragma unroll
        for (int e = 0; e < 4; ++e)
            out[(size_t)(B0 + bm0 + quad * 4 + e) * (D_ * T_) + (size_t)(d0 + l16) * T_] = zfrag[e];
    }
    f32x4 gi_st[3];
    float bhh_l[3], c_l[3];
    for (int t = 0; t < 3; ++t) {
        const int gr = t * H_ + j0 + l16;
        const float* wrow = W_ih + (size_t)gr * D_;
        bhh_l[t] = b_hh[gr];
        float s[4] = {b_ih[gr], b_ih[gr], b_ih[gr], b_ih[gr]};
        float cc = 0.0f;
        for (int d = 0; d < D_; ++d) {
            float wv = wrow[d];
            cc = fmaf(wv, fc_b[d], cc);
            #pragma unroll
            for (int e = 0; e < 4; ++e)
                s[e] = fmaf(wv, z0s[(bm0 + quad * 4 + e) * D_ + d], s[e]);
        }
        c_l[t] = cc;
        #pragma unroll
        for (int e = 0; e < 4; ++e) gi_st[t][e] = s[e];
    }
    const float fcb_l = (l16 < DS) ? fc_b[d0 + l16] : 0.0f;
    __syncthreads();   // z0s dead

    // ===== phase 1: stage Whh_hi, Mhi, fc into LDS (XOR-swizzled) ============
    for (int idx = tid; idx < 48 * H_; idx += NT) {
        int r = idx >> 9, k = idx & (H_ - 1);
        int gr = (r >> 4) * H_ + j0 + (r & 15);
        int ccn = k >> 3, j = k & 7;
        int pos = r * 512 + (((ccn ^ (r & 7)) << 3) | j);
        Whh_s[pos] = (_Float16)W_hh[(size_t)gr * H_ + k];
        Mhi_s[pos] = Mhi_w[(size_t)gr * H_ + k];
    }
    for (int idx = tid; idx < 5 * H_; idx += NT) {
        int r = idx >> 9, k = idx & (H_ - 1);
        int ccn = k >> 3, j = k & 7;
        int pos = r * 512 + (((ccn ^ (r & 7)) << 3) | j);
        float v = (r < DS) ? fc_W[(size_t)(d0 + r) * H_ + k] : 0.0f;
        fcW_s[pos] = (_Float16)v;
    }
    __syncthreads();

    float h_own[4] = {0.f, 0.f, 0.f, 0.f};
    // one counter per (group, wave-class): 16 independent chains
    unsigned* cg = cnt + (g * 2 + wave) * 64;
    const int fcrow = (l16 < DS) ? l16 : 4;
    int mtb[3];
    #pragma unroll
    for (int t = 0; t < 3; ++t) mtb[t] = ((c * 3 + t) * 16) * 512 + (l16 * 4 + quad) * 8;

    for (int i = 1; i <= T_; ++i) {
        const size_t rb = (size_t)((i - 1) & 1) * GHSZ + (size_t)g * (BS * H_);
        const size_t wb = (size_t)(i & 1) * GHSZ + (size_t)g * (BS * H_);
        const u64* rh1 = (const u64*)(h1_g + rb);
        const u64* rh2 = (const u64*)(h2_g + rb);

        // ---- batched A-loads: 64 independent sc1 loads, one base + imm offs --
        const size_t a64 = ((size_t)(bm0 + l16) * H_ + quad * 8) >> 2;
        u64 A1q[32], A2q[32];
        #pragma unroll
        for (int q = 0; q < 32; ++q) A1q[q] = ALD(rh1 + a64 + (q >> 1) * 8 + (q & 1));
        #pragma unroll
        for (int q = 0; q < 32; ++q) A2q[q] = ALD(rh2 + a64 + (q >> 1) * 8 + (q & 1));

        f32x4 acc_gh[3], acc2_gh[3], accM1[3], acc2_gi[3], acc_fc;
        {
            f32x4 z4 = {0.f, 0.f, 0.f, 0.f};
            #pragma unroll
            for (int t = 0; t < 3; ++t) { acc_gh[t] = z4; acc2_gh[t] = z4; accM1[t] = z4; acc2_gi[t] = z4; }
            acc_fc = z4;
        }

        #pragma unroll
        for (int kt = 0; kt < 16; ++kt) {
            union { u64 q[2]; f16x8 v; } A1u, A2u;
            A1u.q[0] = A1q[2 * kt]; A1u.q[1] = A1q[2 * kt + 1];
            A2u.q[0] = A2q[2 * kt]; A2u.q[1] = A2q[2 * kt + 1];
            f16x8 Ah = A1u.v;   // h x 2^11
            f16x8 Al = A2u.v;   // resid x 2^22
            const int chunk = ((kt * 4 + quad) ^ (l16 & 7)) * 8;
            #pragma unroll
            for (int t = 0; t < 3; ++t) {
                const int row = (t * 16 + l16) * 512 + chunk;
                f16x8 Bwh = *(const f16x8*)(Whh_s + row);                      // LDS
                f16x8 Bwl = *(const f16x8*)(WhhL_w + mtb[t] + kt * 512);       // L2
                acc_gh[t]  = MFMA16(Ah, Bwh, acc_gh[t]);    // scale 2^11
                acc2_gh[t] = MFMA16(Al, Bwh, acc2_gh[t]);   // scale 2^22
                acc2_gh[t] = MFMA16(Ah, Bwl, acc2_gh[t]);   // scale 2^22
                f16x8 Bmh = *(const f16x8*)(Mhi_s + row);                      // LDS
                f16x8 Bml = *(const f16x8*)(Mlo_w + mtb[t] + kt * 512);        // L2
                accM1[t]   = MFMA16(Ah, Bmh, accM1[t]);
                acc2_gi[t] = MFMA16(Al, Bmh, acc2_gi[t]);
                acc2_gi[t] = MFMA16(Ah, Bml, acc2_gi[t]);
            }
            f16x8 Bf = *(const f16x8*)(fcW_s + fcrow * 512 + ((kt * 4 + quad) ^ (fcrow & 7)) * 8);
            acc_fc = MFMA16(Ah, Bf, acc_fc);
        }

        // ---- gi_i = gi_{i-1} + M@h_{i-1} + c (needed before gates) ----
        if (i >= 2) {
            #pragma unroll
            for (int t = 0; t < 3; ++t)
                #pragma unroll
                for (int e = 0; e < 4; ++e)
                    gi_st[t][e] += accM1[t][e] * S1 + acc2_gi[t][e] * S2 + c_l[t];
        }

        if (i <= T_ - 1) {
            // ---- gates -> h_i, store (sc1), release-drain, arrive ----
            unsigned short* wh1 = h1_g + wb;
            unsigned short* wh2 = h2_g + wb;
            #pragma unroll
            for (int e = 0; e < 4; ++e) {
                float ghr = acc_gh[0][e] * S1 + acc2_gh[0][e] * S2 + bhh_l[0];
                float ghz = acc_gh[1][e] * S1 + acc2_gh[1][e] * S2 + bhh_l[1];
                float ghn = acc_gh[2][e] * S1 + acc2_gh[2][e] * S2 + bhh_l[2];
                float r  = 1.0f / (1.0f + __expf(-(gi_st[0][e] + ghr)));
                float zg = 1.0f / (1.0f + __expf(-(gi_st[1][e] + ghz)));
                float xn = gi_st[2][e] + r * ghn;
                float hn = (1.0f - zg) * tanhf(xn) + zg * h_own[e];
                h_own[e] = hn;
                const size_t o = (size_t)(bm0 + quad * 4 + e) * H_ + j0 + l16;
                float hs = hn * SC;
                _Float16 a1 = (_Float16)hs;
                _Float16 a2 = (_Float16)((hs - (float)a1) * SC);
                union { _Float16 f; unsigned short u; } c1, c2;
                c1.f = a1; c2.f = a2;
                AST(wh1 + o, c1.u);
                AST(wh2 + o, c2.u);
            }
            asm volatile("s_waitcnt vmcnt(0)" ::: "memory");   // release: stores at MALL
            if (lane == 0)
                __hip_atomic_fetch_add(cg, 1u, __ATOMIC_RELAXED, __HIP_MEMORY_SCOPE_AGENT);
        }

        // ---- z epilogue in the barrier shadow ----
        if (i >= 2 && l16 < DS) {
            const int tcol = i - 1;
            #pragma unroll
            for (int e = 0; e < 4; ++e) {
                zfrag[e] += acc_fc[e] * S1 + fcb_l;
                out[(size_t)(B0 + bm0 + quad * 4 + e) * (D_ * T_) + (size_t)(d0 + l16) * T_ + tcol] = zfrag[e];
            }
        }

        if (i <= T_ - 1) {
            // ---- per-wave spin: 32 arrivals per chain ----
            if (lane == 0) {
                const unsigned target = (unsigned)(CB * i);
                while (ALD(cg) < target) __builtin_amdgcn_s_sleep(1);
            }
            asm volatile("" ::: "memory");   // no reordering across the spin
        }
    }
}

extern "C" void kernel_launch(void* const* d_in, const int* in_sizes, int n_in,
                              void* d_out, int out_size, void* d_ws, size_t ws_size,
                              hipStream_t stream) {
    const float* z    = (const float*)d_in[0];
    // d_in[1] = e : unused by the reference computation
    const float* W_ih = (const float*)d_in[2];
    const float* W_hh = (const float*)d_in[3];
    const float* b_ih = (const float*)d_in[4];
    const float* b_hh = (const float*)d_in[5];
    const float* fc_W = (const float*)d_in[6];
    const float* fc_b = (const float*)d_in[7];
    float* out = (float*)d_out;

    // ws: [0,4K) counters | h1 2x | h2 2x | Mhi | Mlo(tiled) | WhhL(tiled)
    char* w = (char*)d_ws;
    unsigned*       cnt  = (unsigned*)w;
    unsigned short* h1   = (unsigned short*)(w + 4096);
    unsigned short* h2   = (unsigned short*)(w + 4096 + (size_t)4 * GHSZ);
    _Float16*       Mhi  = (_Float16*)(w + 4096 + (size_t)8 * GHSZ);
    _Float16*       Mlo  = (_Float16*)(w + 4096 + (size_t)8 * GHSZ + (size_t)3 * H_ * H_ * 2);
    _Float16*       WhhL = (_Float16*)(w + 4096 + (size_t)8 * GHSZ + (size_t)6 * H_ * H_ * 2);

    // zero counters + h buffers (h_0 = 0); ws re-poisoned before every launch
    hipMemsetAsync(d_ws, 0, 4096 + (size_t)8 * GHSZ, stream);

    hipLaunchKernelGGL(msd_setup_M,  dim3(768), dim3(256), 0, stream, W_ih, fc_W, Mhi, Mlo);
    hipLaunchKernelGGL(msd_setup_WL, dim3(768), dim3(256), 0, stream, W_hh, WhhL);
    hipLaunchKernelGGL(msd_gru_kernel, dim3(NG * CB), dim3(NT), 0, stream,
                       z, W_ih, W_hh, b_ih, b_hh, fc_W, fc_b, out, h1, h2, Mhi, Mlo, WhhL, cnt);
}